// Round 12
// baseline (718.381 us; speedup 1.0000x reference)
//
#include <hip/hip_runtime.h>
#include <hip/hip_cooperative_groups.h>
#include <math.h>

namespace cg = cooperative_groups;

#define BB 16
#define AA 65536
#define GG 32

// workspace layout (bytes)
#define OFF_PACKED   0            // u64[BB*GG]                      4096
#define OFF_HIST     4096         // int[4][BB][256]                 65536
#define OFF_NUMPOS   69632        // int[BB]
#define OFF_LOCSUM   69696        // float[BB]
#define OFF_POSBCE   69760        // float[BB]
#define OFF_PREDCNT  69824        // int[BB]
#define OFF_NEGSUM   69888        // float[BB]
#define OFF_NGT      69952        // int[BB]
#define OFF_MIOU_S   70016        // float
#define OFF_MIOU_C   70020        // int
#define OFF_VK       70080        // float[BB]
#define MEMSET_BYTES 71680        // zero [0, 70KiB)
#define OFF_NEGBCE   2097152      // float[BB*AA]  (fallback path only)

__device__ __forceinline__ float iou_exact(float ax, float ay, float az, float aw,
                                           float area_a,
                                           float gx, float gy, float gz, float gw,
                                           float area_g) {
    float lx = fmaxf(ax, gx), ly = fmaxf(ay, gy);
    float rx = fminf(az, gz), ry = fminf(aw, gw);
    float w = fmaxf(__fsub_rn(rx, lx), 0.0f);
    float h = fmaxf(__fsub_rn(ry, ly), 0.0f);
    float inter = __fmul_rn(w, h);
    float uni = __fsub_rn(__fadd_rn(area_a, area_g), inter);
    return __fdiv_rn(inter, __fadd_rn(uni, 1e-6f));
}

__device__ __forceinline__ float sl1(float x, float y) {
    float d = fabsf(__fsub_rn(x, y));
    return (d < 1.0f) ? __fmul_rn(__fmul_rn(0.5f, d), d) : __fsub_rn(d, 0.5f);
}

__device__ __forceinline__ float loc_term(float4 bp, float4 gb) {
    float pcx = __fmul_rn(__fadd_rn(bp.x, bp.z), 0.5f);
    float pcy = __fmul_rn(__fadd_rn(bp.y, bp.w), 0.5f);
    float pw = __fsub_rn(bp.z, bp.x), ph = __fsub_rn(bp.w, bp.y);
    float gcx = __fmul_rn(__fadd_rn(gb.x, gb.z), 0.5f);
    float gcy = __fmul_rn(__fadd_rn(gb.y, gb.w), 0.5f);
    float gw = __fsub_rn(gb.z, gb.x), gh = __fsub_rn(gb.w, gb.y);
    return __fadd_rn(__fadd_rn(__fadd_rn(sl1(pcx, gcx), sl1(pcy, gcy)), sl1(pw, gw)), sl1(ph, gh));
}

// ---------------- radix-select scan of one 8-bit level (256 threads) ----------------
__device__ __forceinline__ void scan_level(const int* __restrict__ histL, int t,
                                           int* ss, int* sres,
                                           unsigned int* prefix, int* k, int shift) {
    int kk = *k;
    ss[t] = histL[t];
    __syncthreads();
#pragma unroll
    for (int off = 1; off < 256; off <<= 1) {
        int v = (t + off < 256) ? ss[t + off] : 0;
        __syncthreads();
        ss[t] += v;
        __syncthreads();
    }
    if (ss[t] >= kk && (t == 255 || ss[t + 1] < kk)) {
        sres[0] = t;
        sres[1] = (t == 255) ? kk : (kk - ss[t + 1]);
    }
    __syncthreads();
    *prefix |= ((unsigned int)sres[0]) << shift;
    *k = sres[1];
    __syncthreads();
}

// ================= FUSED COOPERATIVE KERNEL =================
struct FParams {
    const float4* bbox; const float* conf; const float4* anchors; const float4* gt;
    unsigned long long* packed; int* hist;
    int* num_pos; float* loc_sum; float* posbce; int* pred_cnt;
    float* negsum; int* ngt; float* miou_s; int* miou_c; float* vk_arr;
    float* out;
};

__global__ __launch_bounds__(256, 4) void k_fused(FParams P) {
    cg::grid_group gridg = cg::this_grid();
    const int b = blockIdx.y, t = threadIdx.x;
    const int base = blockIdx.x * 1024;
    const int lane = t & 63, wv = t >> 6;
    __shared__ unsigned long long red[4][GG];
    __shared__ unsigned int win_s[GG];
    __shared__ int sh[256];
    __shared__ int ss[256];
    __shared__ int sres[2];
    __shared__ float sloc[4], spb[4], sms[4], sfs[4];
    __shared__ int snp[4], spc[4], smc[4], sfc[4];

    // ---- phase 1: IoU sweep, per-anchor argmax, per-gt argmax (split butterflies) ----
    float4 an[4]; float aa[4]; float bi[4]; int bix[4]; float p[4];
#pragma unroll
    for (int j = 0; j < 4; ++j) {
        const int a = base + j * 256 + t;
        an[j] = P.anchors[a];
        p[j] = P.conf[b * AA + a];
        aa[j] = __fmul_rn(__fsub_rn(an[j].z, an[j].x), __fsub_rn(an[j].w, an[j].y));
        bi[j] = -1.0f; bix[j] = 0;
    }
    for (int g = 0; g < GG; g += 2) {
        float4 g0 = P.gt[b * GG + g];
        float4 g1 = P.gt[b * GG + g + 1];
        float ag0 = __fmul_rn(__fsub_rn(g0.z, g0.x), __fsub_rn(g0.w, g0.y));
        float ag1 = __fmul_rn(__fsub_rn(g1.z, g1.x), __fsub_rn(g1.w, g1.y));
        float m0 = -1.0f, m1 = -1.0f;
        unsigned int c0 = 0xFFFFFFFFu, c1 = 0xFFFFFFFFu;
#pragma unroll
        for (int j = 0; j < 4; ++j) {
            const unsigned int a = (unsigned)(base + j * 256 + t);
            float i0 = iou_exact(an[j].x, an[j].y, an[j].z, an[j].w, aa[j],
                                 g0.x, g0.y, g0.z, g0.w, ag0);
            float i1 = iou_exact(an[j].x, an[j].y, an[j].z, an[j].w, aa[j],
                                 g1.x, g1.y, g1.z, g1.w, ag1);
            if (i0 > bi[j]) { bi[j] = i0; bix[j] = g; }
            if (i1 > bi[j]) { bi[j] = i1; bix[j] = g + 1; }
            if (i0 > m0) { m0 = i0; c0 = a; }    // ascending aidx: strict > keeps first
            if (i1 > m1) { m1 = i1; c1 = a; }
        }
        // f32 all-reduce max (iou >= 0, so value order == bit order; equality exact)
        float lm0 = m0, lm1 = m1;
#pragma unroll
        for (int off = 32; off; off >>= 1) {
            m0 = fmaxf(m0, __shfl_xor(m0, off, 64));
            m1 = fmaxf(m1, __shfl_xor(m1, off, 64));
        }
        c0 = (lm0 == m0) ? c0 : 0xFFFFFFFFu;
        c1 = (lm1 == m1) ? c1 : 0xFFFFFFFFu;
#pragma unroll
        for (int off = 32; off; off >>= 1) {
            c0 = min(c0, __shfl_xor(c0, off, 64));
            c1 = min(c1, __shfl_xor(c1, off, 64));
        }
        if (lane == 0) {
            red[wv][g]     = ((unsigned long long)__float_as_uint(m0) << 32)
                           | (unsigned long long)(0xFFFFFFFFu - c0);
            red[wv][g + 1] = ((unsigned long long)__float_as_uint(m1) << 32)
                           | (unsigned long long)(0xFFFFFFFFu - c1);
        }
    }
    __syncthreads();
    if (t < GG) {
        unsigned long long q = red[0][t];
#pragma unroll
        for (int w = 1; w < 4; ++w) if (red[w][t] > q) q = red[w][t];
        atomicMax(&P.packed[b * GG + t], q);
    }
    // phase 1.5: pred_cnt + (b==15) mean-iou (independent of force)
    {
        int pc = 0, mc = 0; float ms = 0.0f;
#pragma unroll
        for (int j = 0; j < 4; ++j) {
            pc += (p[j] > 0.5f) ? 1 : 0;
            if (b == BB - 1 && bi[j] > 0.0f) { ms += bi[j]; mc++; }
        }
#pragma unroll
        for (int off = 32; off; off >>= 1) {
            pc += __shfl_xor(pc, off, 64);
            if (b == BB - 1) { ms += __shfl_xor(ms, off, 64); mc += __shfl_xor(mc, off, 64); }
        }
        if (lane == 0) { spc[wv] = pc; sms[wv] = ms; smc[wv] = mc; }
        __syncthreads();
        if (t == 0) {
            int C = spc[0] + spc[1] + spc[2] + spc[3];
            if (C) atomicAdd(&P.pred_cnt[b], C);
            if (b == BB - 1) {
                float S = sms[0] + sms[1] + sms[2] + sms[3];
                int   M = smc[0] + smc[1] + smc[2] + smc[3];
                if (S != 0.0f) atomicAdd(P.miou_s, S);
                if (M) atomicAdd(P.miou_c, M);
            }
        }
    }
    gridg.sync();  // S1: packed winners final

    // ---- phase 2: force-membership, pos/bce/loc, hist level 0 (from registers) ----
    if (t < GG) win_s[t] = 0xFFFFFFFFu - (unsigned int)(P.packed[b * GG + t] & 0xFFFFFFFFull);
    sh[t] = 0;
    __syncthreads();
    float nb[4];
    {
        float loc = 0.0f, pb = 0.0f; int np_ = 0;
#pragma unroll
        for (int j = 0; j < 4; ++j) {
            const unsigned int a = (unsigned)(base + j * 256 + t);
            const int idx = b * AA + (int)a;
            bool member = false;
#pragma unroll
            for (int g = 0; g < GG; ++g) member |= (win_s[g] == a);
            bool pos = (bi[j] > 0.5f) || member;
            if (pos) {
                float bce = -fmaxf(logf(p[j]), -100.0f);
                nb[j] = 0.0f;
                pb += bce; np_++;
                loc += loc_term(P.bbox[idx], P.gt[b * GG + bix[j]]);
            } else {
                nb[j] = -fmaxf(log1pf(-p[j]), -100.0f);
                atomicAdd(&sh[__float_as_uint(nb[j]) >> 24], 1);
            }
        }
#pragma unroll
        for (int off = 32; off; off >>= 1) {
            loc += __shfl_xor(loc, off, 64);
            pb  += __shfl_xor(pb, off, 64);
            np_ += __shfl_xor(np_, off, 64);
        }
        if (lane == 0) { sloc[wv] = loc; spb[wv] = pb; snp[wv] = np_; }
        __syncthreads();
        if (t == 0) {
            float L = sloc[0] + sloc[1] + sloc[2] + sloc[3];
            float PP = spb[0] + spb[1] + spb[2] + spb[3];
            int   N = snp[0] + snp[1] + snp[2] + snp[3];
            if (L != 0.0f) atomicAdd(&P.loc_sum[b], L);
            if (PP != 0.0f) atomicAdd(&P.posbce[b], PP);
            if (N) atomicAdd(&P.num_pos[b], N);
        }
        if (sh[t]) atomicAdd(&P.hist[(0 * BB + b) * 256 + t], sh[t]);
    }
    gridg.sync();  // S2: num_pos + hist0 final

    // ---- phase 3: radix levels 1..3 from registers ----
    int np = P.num_pos[b];
    int k = min(3 * np, AA - np);
    const bool act = (k > 0);
    unsigned int prefix = 0;
    if (act) scan_level(&P.hist[(0 * BB + b) * 256], t, ss, sres, &prefix, &k, 24);
    // level 1
    sh[t] = 0; __syncthreads();
    if (act) {
#pragma unroll
        for (int j = 0; j < 4; ++j) {
            unsigned int bits = __float_as_uint(nb[j]);
            if ((bits >> 24) == (prefix >> 24)) atomicAdd(&sh[(bits >> 16) & 0xFFu], 1);
        }
    }
    __syncthreads();
    if (act && sh[t]) atomicAdd(&P.hist[(1 * BB + b) * 256 + t], sh[t]);
    gridg.sync();  // S3
    if (act) scan_level(&P.hist[(1 * BB + b) * 256], t, ss, sres, &prefix, &k, 16);
    // level 2
    sh[t] = 0; __syncthreads();
    if (act) {
#pragma unroll
        for (int j = 0; j < 4; ++j) {
            unsigned int bits = __float_as_uint(nb[j]);
            if ((bits >> 16) == (prefix >> 16)) atomicAdd(&sh[(bits >> 8) & 0xFFu], 1);
        }
    }
    __syncthreads();
    if (act && sh[t]) atomicAdd(&P.hist[(2 * BB + b) * 256 + t], sh[t]);
    gridg.sync();  // S4
    if (act) scan_level(&P.hist[(2 * BB + b) * 256], t, ss, sres, &prefix, &k, 8);
    // level 3
    sh[t] = 0; __syncthreads();
    if (act) {
#pragma unroll
        for (int j = 0; j < 4; ++j) {
            unsigned int bits = __float_as_uint(nb[j]);
            if ((bits >> 8) == (prefix >> 8)) atomicAdd(&sh[bits & 0xFFu], 1);
        }
    }
    __syncthreads();
    if (act && sh[t]) atomicAdd(&P.hist[(3 * BB + b) * 256 + t], sh[t]);
    gridg.sync();  // S5
    if (act) scan_level(&P.hist[(3 * BB + b) * 256], t, ss, sres, &prefix, &k, 0);
    const float vk = __uint_as_float(prefix);
    if (act && blockIdx.x == 0 && t == 0) P.vk_arr[b] = vk;

    // ---- phase 4: sum of values strictly greater than vk ----
    {
        float s = 0.0f; int c = 0;
        if (act) {
#pragma unroll
            for (int j = 0; j < 4; ++j) if (nb[j] > vk) { s += nb[j]; c++; }
        }
#pragma unroll
        for (int off = 32; off; off >>= 1) { s += __shfl_xor(s, off, 64); c += __shfl_xor(c, off, 64); }
        if (lane == 0) { sfs[wv] = s; sfc[wv] = c; }
        __syncthreads();
        if (t == 0) {
            float S = sfs[0] + sfs[1] + sfs[2] + sfs[3];
            int   C = sfc[0] + sfc[1] + sfc[2] + sfc[3];
            if (S != 0.0f) atomicAdd(&P.negsum[b], S);
            if (C) atomicAdd(&P.ngt[b], C);
        }
    }
    gridg.sync();  // S6

    // ---- phase 5: final combine ----
    if (blockIdx.x == 0 && b == 0 && t == 0) {
        int npos_t = 0; float loc_t = 0.0f, conf_t = 0.0f, cnt_t = 0.0f;
        for (int bb2 = 0; bb2 < BB; ++bb2) {
            int np2 = P.num_pos[bb2];
            int k0 = min(3 * np2, AA - np2);
            float add = P.posbce[bb2] + P.negsum[bb2];
            if (k0 > 0) add += (float)(k0 - P.ngt[bb2]) * P.vk_arr[bb2];
            conf_t += add;
            npos_t += np2;
            loc_t += P.loc_sum[bb2];
            float diff = fabsf((float)(P.pred_cnt[bb2] - GG));
            cnt_t += (diff <= 3.0f) ? diff * 0.2f
                                    : 0.6f + 0.2f * logf(fmaxf(diff - 2.0f, 1.0f));
        }
        float total_count = cnt_t / (float)BB;
        float npos = (float)max(1, npos_t);
        float total_loc = loc_t / npos;
        float total_conf = conf_t / npos;
        int C = *P.miou_c;
        float mean_iou = (C > 0) ? (*P.miou_s / (float)max(C, 1)) : 0.1f;
        float q = fminf(fmaxf(1.0f - mean_iou, 0.1f), 0.9f);
        float dyn = 1.0f + q;
        P.out[0] = dyn * total_loc + total_conf + 0.2f * total_count;
        P.out[1] = total_conf;
        P.out[2] = total_loc;
        P.out[3] = total_count;
        P.out[4] = mean_iou;
    }
}

// ================= FALLBACK PATH (Round-6 kernels, verbatim) =================

__global__ __launch_bounds__(256) void k_main(const float4* __restrict__ bbox,
                                              const float* __restrict__ conf,
                                              const float4* __restrict__ anchors,
                                              const float4* __restrict__ gt,
                                              unsigned long long* __restrict__ packed,
                                              float* __restrict__ neg_bce,
                                              int* __restrict__ hist0,
                                              int* __restrict__ num_pos,
                                              float* __restrict__ loc_sum,
                                              float* __restrict__ posbce,
                                              int* __restrict__ pred_cnt,
                                              float* __restrict__ miou_s,
                                              int* __restrict__ miou_c) {
    const int b = blockIdx.y, t = threadIdx.x;
    const int base = blockIdx.x * 1024;
    __shared__ unsigned long long red[4][GG];
    __shared__ int sh[256];
    __shared__ float sloc[4], spb[4], sms[4];
    __shared__ int snp[4], spc[4], smc[4];
    sh[t] = 0;
    float4 an[4]; float aa[4]; float bi[4]; int bix[4]; int aidx[4];
#pragma unroll
    for (int j = 0; j < 4; ++j) {
        aidx[j] = base + j * 256 + t;
        an[j] = anchors[aidx[j]];
        aa[j] = __fmul_rn(__fsub_rn(an[j].z, an[j].x), __fsub_rn(an[j].w, an[j].y));
        bi[j] = -1.0f; bix[j] = 0;
    }
    __syncthreads();
    const int lane = t & 63, wv = t >> 6;
    for (int g = 0; g < GG; g += 2) {
        float4 g0 = gt[b * GG + g];
        float4 g1 = gt[b * GG + g + 1];
        float ag0 = __fmul_rn(__fsub_rn(g0.z, g0.x), __fsub_rn(g0.w, g0.y));
        float ag1 = __fmul_rn(__fsub_rn(g1.z, g1.x), __fsub_rn(g1.w, g1.y));
        unsigned long long pk0 = 0ull, pk1 = 0ull;
#pragma unroll
        for (int j = 0; j < 4; ++j) {
            float i0 = iou_exact(an[j].x, an[j].y, an[j].z, an[j].w, aa[j],
                                 g0.x, g0.y, g0.z, g0.w, ag0);
            float i1 = iou_exact(an[j].x, an[j].y, an[j].z, an[j].w, aa[j],
                                 g1.x, g1.y, g1.z, g1.w, ag1);
            if (i0 > bi[j]) { bi[j] = i0; bix[j] = g; }
            if (i1 > bi[j]) { bi[j] = i1; bix[j] = g + 1; }
            unsigned long long p0 = ((unsigned long long)__float_as_uint(i0) << 32)
                                  | (unsigned long long)(0xFFFFFFFFu - (unsigned)aidx[j]);
            unsigned long long p1 = ((unsigned long long)__float_as_uint(i1) << 32)
                                  | (unsigned long long)(0xFFFFFFFFu - (unsigned)aidx[j]);
            if (p0 > pk0) pk0 = p0;
            if (p1 > pk1) pk1 = p1;
        }
#pragma unroll
        for (int off = 32; off; off >>= 1) {
            unsigned long long q0 = __shfl_xor(pk0, off, 64);
            unsigned long long q1 = __shfl_xor(pk1, off, 64);
            if (q0 > pk0) pk0 = q0;
            if (q1 > pk1) pk1 = q1;
        }
        if (lane == 0) { red[wv][g] = pk0; red[wv][g + 1] = pk1; }
    }
    float loc = 0.0f, pb = 0.0f, ms = 0.0f;
    int np_ = 0, pc = 0, mc = 0;
#pragma unroll
    for (int j = 0; j < 4; ++j) {
        const int idx = b * AA + aidx[j];
        float p = conf[idx];
        bool pos = bi[j] > 0.5f;
        float bce, nb;
        if (pos) { bce = -fmaxf(logf(p), -100.0f); nb = 0.0f; }
        else     { bce = -fmaxf(log1pf(-p), -100.0f); nb = bce; }
        neg_bce[idx] = nb;
        if (!pos) atomicAdd(&sh[__float_as_uint(nb) >> 24], 1);
        if (pos) {
            loc += loc_term(bbox[idx], gt[b * GG + bix[j]]);
            pb += bce;
            np_++;
        }
        pc += (p > 0.5f) ? 1 : 0;
        if (b == BB - 1 && bi[j] > 0.0f) { ms += bi[j]; mc++; }
    }
#pragma unroll
    for (int off = 32; off; off >>= 1) {
        loc += __shfl_xor(loc, off, 64);
        pb  += __shfl_xor(pb, off, 64);
        np_ += __shfl_xor(np_, off, 64);
        pc  += __shfl_xor(pc, off, 64);
        if (b == BB - 1) { ms += __shfl_xor(ms, off, 64); mc += __shfl_xor(mc, off, 64); }
    }
    if (lane == 0) {
        sloc[wv] = loc; spb[wv] = pb; snp[wv] = np_; spc[wv] = pc;
        sms[wv] = ms; smc[wv] = mc;
    }
    __syncthreads();
    if (t == 0) {
        float L = sloc[0] + sloc[1] + sloc[2] + sloc[3];
        float P = spb[0] + spb[1] + spb[2] + spb[3];
        int   N = snp[0] + snp[1] + snp[2] + snp[3];
        int   C = spc[0] + spc[1] + spc[2] + spc[3];
        if (L != 0.0f) atomicAdd(&loc_sum[b], L);
        if (P != 0.0f) atomicAdd(&posbce[b], P);
        if (N) atomicAdd(&num_pos[b], N);
        if (C) atomicAdd(&pred_cnt[b], C);
        if (b == BB - 1) {
            float S = sms[0] + sms[1] + sms[2] + sms[3];
            int   M = smc[0] + smc[1] + smc[2] + smc[3];
            if (S != 0.0f) atomicAdd(miou_s, S);
            if (M) atomicAdd(miou_c, M);
        }
    }
    if (t < GG) {
        unsigned long long p = red[0][t];
#pragma unroll
        for (int w = 1; w < 4; ++w) if (red[w][t] > p) p = red[w][t];
        atomicMax(&packed[b * GG + t], p);
    }
    if (sh[t]) atomicAdd(&hist0[b * 256 + t], sh[t]);
}

__global__ __launch_bounds__(512) void k_force(const float4* __restrict__ bbox,
                                               const float* __restrict__ conf,
                                               const float4* __restrict__ anchors,
                                               const float4* __restrict__ gt,
                                               const unsigned long long* __restrict__ packed,
                                               float* __restrict__ neg_bce,
                                               int* __restrict__ hist0,
                                               int* __restrict__ num_pos,
                                               float* __restrict__ loc_sum,
                                               float* __restrict__ posbce) {
    const int t = threadIdx.x;
    const int b = t >> 5, g = t & 31;
    __shared__ unsigned int win[BB][GG];
    unsigned int a = 0xFFFFFFFFu - (unsigned int)(packed[b * GG + g] & 0xFFFFFFFFull);
    win[b][g] = a;
    __syncthreads();
    bool dup = false;
    for (int gp = 0; gp < g; ++gp) dup |= (win[b][gp] == a);
    if (dup) return;
    float4 an = anchors[a];
    float aa = __fmul_rn(__fsub_rn(an.z, an.x), __fsub_rn(an.w, an.y));
    float bi = -1.0f; int bix = 0;
    for (int gg = 0; gg < GG; ++gg) {
        float4 gv = gt[b * GG + gg];
        float ag = __fmul_rn(__fsub_rn(gv.z, gv.x), __fsub_rn(gv.w, gv.y));
        float iou = iou_exact(an.x, an.y, an.z, an.w, aa, gv.x, gv.y, gv.z, gv.w, ag);
        if (iou > bi) { bi = iou; bix = gg; }
    }
    if (bi > 0.5f) return;
    const int idx = b * AA + a;
    float p = conf[idx];
    float nb = -fmaxf(log1pf(-p), -100.0f);
    atomicSub(&hist0[b * 256 + (int)(__float_as_uint(nb) >> 24)], 1);
    neg_bce[idx] = 0.0f;
    float bce = -fmaxf(logf(p), -100.0f);
    atomicAdd(&posbce[b], bce);
    atomicAdd(&num_pos[b], 1);
    atomicAdd(&loc_sum[b], loc_term(bbox[idx], gt[b * GG + bix]));
}

__global__ __launch_bounds__(256) void k_hist(const float* __restrict__ neg_bce,
                                              int* __restrict__ hist,
                                              const int* __restrict__ num_pos,
                                              int pass) {
    const int b = blockIdx.y, t = threadIdx.x;
    __shared__ int ss[256];
    __shared__ int sres[2];
    __shared__ int sh[256];
    int np_ = num_pos[b];
    int k = min(3 * np_, AA - np_);
    if (k <= 0) return;
    unsigned int prefix = 0;
    for (int L = 0; L < pass; ++L)
        scan_level(&hist[(L * BB + b) * 256], t, ss, sres, &prefix, &k, 24 - 8 * L);
    sh[t] = 0;
    __syncthreads();
    const unsigned int pmask = 0xFFFFFFFFu << (32 - 8 * pass);
    const int shift = 24 - 8 * pass;
    for (int a = blockIdx.x * 256 + t; a < AA; a += gridDim.x * 256) {
        unsigned int bits = __float_as_uint(neg_bce[b * AA + a]);
        if ((bits & pmask) == prefix) atomicAdd(&sh[(bits >> shift) & 0xFFu], 1);
    }
    __syncthreads();
    if (sh[t]) atomicAdd(&hist[(pass * BB + b) * 256 + t], sh[t]);
}

__global__ __launch_bounds__(256) void k_topk(const float* __restrict__ neg_bce,
                                              const int* __restrict__ hist,
                                              const int* __restrict__ num_pos,
                                              float* __restrict__ negsum,
                                              int* __restrict__ ngt,
                                              float* __restrict__ vk_arr) {
    const int b = blockIdx.y, t = threadIdx.x;
    __shared__ int ss[256];
    __shared__ int sres[2];
    __shared__ float sfs[4];
    __shared__ int sfc[4];
    int np_ = num_pos[b];
    int k = min(3 * np_, AA - np_);
    if (k <= 0) return;
    unsigned int prefix = 0;
    for (int L = 0; L < 4; ++L)
        scan_level(&hist[(L * BB + b) * 256], t, ss, sres, &prefix, &k, 24 - 8 * L);
    const float vk = __uint_as_float(prefix);
    if (blockIdx.x == 0 && t == 0) vk_arr[b] = vk;
    float s = 0.0f; int c = 0;
    for (int a = blockIdx.x * 256 + t; a < AA; a += gridDim.x * 256) {
        float v = neg_bce[b * AA + a];
        if (v > vk) { s += v; c++; }
    }
#pragma unroll
    for (int off = 32; off; off >>= 1) { s += __shfl_xor(s, off, 64); c += __shfl_xor(c, off, 64); }
    const int lane = t & 63, wv = t >> 6;
    if (lane == 0) { sfs[wv] = s; sfc[wv] = c; }
    __syncthreads();
    if (t == 0) {
        float S = sfs[0] + sfs[1] + sfs[2] + sfs[3];
        int   C = sfc[0] + sfc[1] + sfc[2] + sfc[3];
        if (S != 0.0f) atomicAdd(&negsum[b], S);
        if (C) atomicAdd(&ngt[b], C);
    }
}

__global__ void k_final(const int* __restrict__ num_pos,
                        const float* __restrict__ loc_sum,
                        const float* __restrict__ posbce,
                        const float* __restrict__ negsum,
                        const int* __restrict__ ngt,
                        const float* __restrict__ vk_arr,
                        const int* __restrict__ pred_cnt,
                        const float* __restrict__ miou_s,
                        const int* __restrict__ miou_c,
                        float* __restrict__ out) {
    if (threadIdx.x == 0) {
        int npos_t = 0; float loc_t = 0.0f, conf_t = 0.0f, cnt_t = 0.0f;
        for (int b = 0; b < BB; ++b) {
            int np_ = num_pos[b];
            int k0 = min(3 * np_, AA - np_);
            float add = posbce[b] + negsum[b];
            if (k0 > 0) add += (float)(k0 - ngt[b]) * vk_arr[b];
            conf_t += add;
            npos_t += np_;
            loc_t += loc_sum[b];
            float diff = fabsf((float)(pred_cnt[b] - GG));
            cnt_t += (diff <= 3.0f) ? diff * 0.2f
                                    : 0.6f + 0.2f * logf(fmaxf(diff - 2.0f, 1.0f));
        }
        float total_count = cnt_t / (float)BB;
        float npos = (float)max(1, npos_t);
        float total_loc = loc_t / npos;
        float total_conf = conf_t / npos;
        int C = *miou_c;
        float mean_iou = (C > 0) ? (*miou_s / (float)max(C, 1)) : 0.1f;
        float q = fminf(fmaxf(1.0f - mean_iou, 0.1f), 0.9f);
        float dyn = 1.0f + q;
        out[0] = dyn * total_loc + total_conf + 0.2f * total_count;
        out[1] = total_conf;
        out[2] = total_loc;
        out[3] = total_count;
        out[4] = mean_iou;
    }
}

extern "C" void kernel_launch(void* const* d_in, const int* in_sizes, int n_in,
                              void* d_out, int out_size, void* d_ws, size_t ws_size,
                              hipStream_t stream) {
    (void)in_sizes; (void)n_in; (void)out_size; (void)ws_size;
    const float* bbox    = (const float*)d_in[0];
    const float* conf    = (const float*)d_in[1];
    const float* anchors = (const float*)d_in[2];
    const float* gt      = (const float*)d_in[3];
    char* ws = (char*)d_ws;
    unsigned long long* packed = (unsigned long long*)(ws + OFF_PACKED);
    int*   hist     = (int*)(ws + OFF_HIST);
    int*   num_pos  = (int*)(ws + OFF_NUMPOS);
    float* loc_sum  = (float*)(ws + OFF_LOCSUM);
    float* posbce   = (float*)(ws + OFF_POSBCE);
    int*   pred_cnt = (int*)(ws + OFF_PREDCNT);
    float* negsum   = (float*)(ws + OFF_NEGSUM);
    int*   ngt      = (int*)(ws + OFF_NGT);
    float* miou_s   = (float*)(ws + OFF_MIOU_S);
    int*   miou_c   = (int*)(ws + OFF_MIOU_C);
    float* vk_arr   = (float*)(ws + OFF_VK);
    float* neg_bce  = (float*)(ws + OFF_NEGBCE);

    hipMemsetAsync(d_ws, 0, MEMSET_BYTES, stream);

    FParams fp;
    fp.bbox = (const float4*)bbox; fp.conf = conf;
    fp.anchors = (const float4*)anchors; fp.gt = (const float4*)gt;
    fp.packed = packed; fp.hist = hist;
    fp.num_pos = num_pos; fp.loc_sum = loc_sum; fp.posbce = posbce; fp.pred_cnt = pred_cnt;
    fp.negsum = negsum; fp.ngt = ngt; fp.miou_s = miou_s; fp.miou_c = miou_c;
    fp.vk_arr = vk_arr; fp.out = (float*)d_out;
    void* kargs[] = { (void*)&fp };

    hipError_t err = hipLaunchCooperativeKernel((const void*)k_fused, dim3(64, BB), dim3(256),
                                                kargs, 0, stream);
    if (err != hipSuccess) {
        (void)hipGetLastError();  // clear error state
        // fallback: proven multi-kernel chain (Round-6 behavior)
        k_main<<<dim3(64, BB), 256, 0, stream>>>((const float4*)bbox, conf,
                                                 (const float4*)anchors, (const float4*)gt,
                                                 packed, neg_bce,
                                                 hist, num_pos, loc_sum, posbce, pred_cnt,
                                                 miou_s, miou_c);
        k_force<<<1, 512, 0, stream>>>((const float4*)bbox, conf,
                                       (const float4*)anchors, (const float4*)gt,
                                       packed, neg_bce, hist, num_pos, loc_sum, posbce);
        for (int pass = 1; pass <= 3; ++pass)
            k_hist<<<dim3(64, BB), 256, 0, stream>>>(neg_bce, hist, num_pos, pass);
        k_topk<<<dim3(64, BB), 256, 0, stream>>>(neg_bce, hist, num_pos, negsum, ngt, vk_arr);
        k_final<<<1, 64, 0, stream>>>(num_pos, loc_sum, posbce, negsum, ngt, vk_arr,
                                      pred_cnt, miou_s, miou_c, (float*)d_out);
    }
}

// Round 13
// 264.364 us; speedup vs baseline: 2.7174x; 2.7174x over previous
//
#include <hip/hip_runtime.h>
#include <math.h>

#define BB 16
#define AA 65536
#define GG 32

// workspace layout (bytes)
#define OFF_PACKED   0            // u64[BB*GG]                      4096
#define OFF_HIST     4096         // int[BB][256] (level 0 only)     16384
#define OFF_NUMPOS   69632        // int[BB]
#define OFF_LOCSUM   69696        // float[BB]
#define OFF_POSBCE   69760        // float[BB]
#define OFF_PREDCNT  69824        // int[BB]
#define OFF_NEGSUM   69888        // float[BB]
#define OFF_NGT      69952        // int[BB]
#define OFF_MIOU_S   70016        // float
#define OFF_MIOU_C   70020        // int
#define OFF_VK       70080        // float[BB]
#define MEMSET_BYTES 71680        // zero [0, 70KiB)
#define OFF_NEGBCE   2097152      // float[BB*AA]                    4 MiB

__device__ __forceinline__ float iou_exact(float ax, float ay, float az, float aw,
                                           float area_a,
                                           float gx, float gy, float gz, float gw,
                                           float area_g) {
    float lx = fmaxf(ax, gx), ly = fmaxf(ay, gy);
    float rx = fminf(az, gz), ry = fminf(aw, gw);
    float w = fmaxf(__fsub_rn(rx, lx), 0.0f);
    float h = fmaxf(__fsub_rn(ry, ly), 0.0f);
    float inter = __fmul_rn(w, h);
    float uni = __fsub_rn(__fadd_rn(area_a, area_g), inter);
    return __fdiv_rn(inter, __fadd_rn(uni, 1e-6f));
}

__device__ __forceinline__ float sl1(float x, float y) {
    float d = fabsf(__fsub_rn(x, y));
    return (d < 1.0f) ? __fmul_rn(__fmul_rn(0.5f, d), d) : __fsub_rn(d, 0.5f);
}

__device__ __forceinline__ float loc_term(float4 bp, float4 gb) {
    float pcx = __fmul_rn(__fadd_rn(bp.x, bp.z), 0.5f);
    float pcy = __fmul_rn(__fadd_rn(bp.y, bp.w), 0.5f);
    float pw = __fsub_rn(bp.z, bp.x), ph = __fsub_rn(bp.w, bp.y);
    float gcx = __fmul_rn(__fadd_rn(gb.x, gb.z), 0.5f);
    float gcy = __fmul_rn(__fadd_rn(gb.y, gb.w), 0.5f);
    float gw = __fsub_rn(gb.z, gb.x), gh = __fsub_rn(gb.w, gb.y);
    return __fadd_rn(__fadd_rn(__fadd_rn(sl1(pcx, gcx), sl1(pcy, gcy)), sl1(pw, gw)), sl1(ph, gh));
}

// ---------------- radix-select scan of one 8-bit level (256 threads) ----------------
__device__ __forceinline__ void scan_level(const int* __restrict__ histL, int t,
                                           int* ss, int* sres,
                                           unsigned int* prefix, int* k, int shift) {
    int kk = *k;
    ss[t] = histL[t];
    __syncthreads();
#pragma unroll
    for (int off = 1; off < 256; off <<= 1) {
        int v = (t + off < 256) ? ss[t + off] : 0;
        __syncthreads();
        ss[t] += v;
        __syncthreads();
    }
    if (ss[t] >= kk && (t == 255 || ss[t + 1] < kk)) {
        sres[0] = t;
        sres[1] = (t == 255) ? kk : (kk - ss[t + 1]);
    }
    __syncthreads();
    *prefix |= ((unsigned int)sres[0]) << shift;
    *k = sres[1];
    __syncthreads();
}

// ---------------- K1: fused anchor pass (split butterflies) ----------------
// grid (64, BB), 256 threads, 4 anchors per thread.
__global__ __launch_bounds__(256) void k_main(const float4* __restrict__ bbox,
                                              const float* __restrict__ conf,
                                              const float4* __restrict__ anchors,
                                              const float4* __restrict__ gt,
                                              unsigned long long* __restrict__ packed,
                                              float* __restrict__ neg_bce,
                                              int* __restrict__ hist0,
                                              int* __restrict__ num_pos,
                                              float* __restrict__ loc_sum,
                                              float* __restrict__ posbce,
                                              int* __restrict__ pred_cnt,
                                              float* __restrict__ miou_s,
                                              int* __restrict__ miou_c) {
    const int b = blockIdx.y, t = threadIdx.x;
    const int base = blockIdx.x * 1024;
    __shared__ unsigned long long red[4][GG];
    __shared__ int sh[256];
    __shared__ float sloc[4], spb[4], sms[4];
    __shared__ int snp[4], spc[4], smc[4];
    sh[t] = 0;
    float4 an[4]; float aa[4]; float bi[4]; int bix[4]; int aidx[4];
#pragma unroll
    for (int j = 0; j < 4; ++j) {
        aidx[j] = base + j * 256 + t;
        an[j] = anchors[aidx[j]];
        aa[j] = __fmul_rn(__fsub_rn(an[j].z, an[j].x), __fsub_rn(an[j].w, an[j].y));
        bi[j] = -1.0f; bix[j] = 0;
    }
    __syncthreads();
    const int lane = t & 63, wv = t >> 6;
    for (int g = 0; g < GG; g += 2) {
        float4 g0 = gt[b * GG + g];
        float4 g1 = gt[b * GG + g + 1];
        float ag0 = __fmul_rn(__fsub_rn(g0.z, g0.x), __fsub_rn(g0.w, g0.y));
        float ag1 = __fmul_rn(__fsub_rn(g1.z, g1.x), __fsub_rn(g1.w, g1.y));
        float m0 = -1.0f, m1 = -1.0f;
        unsigned int c0 = 0xFFFFFFFFu, c1 = 0xFFFFFFFFu;
#pragma unroll
        for (int j = 0; j < 4; ++j) {
            float i0 = iou_exact(an[j].x, an[j].y, an[j].z, an[j].w, aa[j],
                                 g0.x, g0.y, g0.z, g0.w, ag0);
            float i1 = iou_exact(an[j].x, an[j].y, an[j].z, an[j].w, aa[j],
                                 g1.x, g1.y, g1.z, g1.w, ag1);
            if (i0 > bi[j]) { bi[j] = i0; bix[j] = g; }       // ascending g: strict > keeps first
            if (i1 > bi[j]) { bi[j] = i1; bix[j] = g + 1; }
            if (i0 > m0) { m0 = i0; c0 = (unsigned)aidx[j]; } // ascending aidx within lane
            if (i1 > m1) { m1 = i1; c1 = (unsigned)aidx[j]; }
        }
        // split all-reduce: f32 max (iou>=0 exact), then min index among maximizers
        float lm0 = m0, lm1 = m1;
#pragma unroll
        for (int off = 32; off; off >>= 1) {
            m0 = fmaxf(m0, __shfl_xor(m0, off, 64));
            m1 = fmaxf(m1, __shfl_xor(m1, off, 64));
        }
        c0 = (lm0 == m0) ? c0 : 0xFFFFFFFFu;
        c1 = (lm1 == m1) ? c1 : 0xFFFFFFFFu;
#pragma unroll
        for (int off = 32; off; off >>= 1) {
            c0 = min(c0, __shfl_xor(c0, off, 64));
            c1 = min(c1, __shfl_xor(c1, off, 64));
        }
        if (lane == 0) {
            red[wv][g]     = ((unsigned long long)__float_as_uint(m0) << 32)
                           | (unsigned long long)(0xFFFFFFFFu - c0);
            red[wv][g + 1] = ((unsigned long long)__float_as_uint(m1) << 32)
                           | (unsigned long long)(0xFFFFFFFFu - c1);
        }
    }
    // per-anchor epilogue (pos EXCLUDES force — fixed by k_select)
    float loc = 0.0f, pb = 0.0f, ms = 0.0f;
    int np_ = 0, pc = 0, mc = 0;
#pragma unroll
    for (int j = 0; j < 4; ++j) {
        const int idx = b * AA + aidx[j];
        float p = conf[idx];
        bool pos = bi[j] > 0.5f;
        float bce, nb;
        if (pos) { bce = -fmaxf(logf(p), -100.0f); nb = 0.0f; }
        else     { bce = -fmaxf(log1pf(-p), -100.0f); nb = bce; }
        neg_bce[idx] = nb;
        if (!pos) atomicAdd(&sh[__float_as_uint(nb) >> 24], 1);
        if (pos) {
            loc += loc_term(bbox[idx], gt[b * GG + bix[j]]);
            pb += bce;
            np_++;
        }
        pc += (p > 0.5f) ? 1 : 0;
        if (b == BB - 1 && bi[j] > 0.0f) { ms += bi[j]; mc++; }
    }
#pragma unroll
    for (int off = 32; off; off >>= 1) {
        loc += __shfl_xor(loc, off, 64);
        pb  += __shfl_xor(pb, off, 64);
        np_ += __shfl_xor(np_, off, 64);
        pc  += __shfl_xor(pc, off, 64);
        if (b == BB - 1) { ms += __shfl_xor(ms, off, 64); mc += __shfl_xor(mc, off, 64); }
    }
    if (lane == 0) {
        sloc[wv] = loc; spb[wv] = pb; snp[wv] = np_; spc[wv] = pc;
        sms[wv] = ms; smc[wv] = mc;
    }
    __syncthreads();
    if (t == 0) {
        float L = sloc[0] + sloc[1] + sloc[2] + sloc[3];
        float P = spb[0] + spb[1] + spb[2] + spb[3];
        int   N = snp[0] + snp[1] + snp[2] + snp[3];
        int   C = spc[0] + spc[1] + spc[2] + spc[3];
        if (L != 0.0f) atomicAdd(&loc_sum[b], L);
        if (P != 0.0f) atomicAdd(&posbce[b], P);
        if (N) atomicAdd(&num_pos[b], N);
        if (C) atomicAdd(&pred_cnt[b], C);
        if (b == BB - 1) {
            float S = sms[0] + sms[1] + sms[2] + sms[3];
            int   M = smc[0] + smc[1] + smc[2] + smc[3];
            if (S != 0.0f) atomicAdd(miou_s, S);
            if (M) atomicAdd(miou_c, M);
        }
    }
    if (t < GG) {
        unsigned long long q = red[0][t];
#pragma unroll
        for (int w = 1; w < 4; ++w) if (red[w][t] > q) q = red[w][t];
        atomicMax(&packed[b * GG + t], q);
    }
    if (sh[t]) atomicAdd(&hist0[b * 256 + t], sh[t]);
}

// ---------------- K2: fused force-patch + radix select + topk sum (1 block / image) ----------------
__global__ __launch_bounds__(256) void k_select(const float4* __restrict__ bbox,
                                                const float* __restrict__ conf,
                                                const float4* __restrict__ anchors,
                                                const float4* __restrict__ gt,
                                                const unsigned long long* __restrict__ packed,
                                                const int* __restrict__ hist0,
                                                float* __restrict__ neg_bce,
                                                int* __restrict__ num_pos,
                                                float* __restrict__ loc_sum,
                                                float* __restrict__ posbce,
                                                float* __restrict__ negsum,
                                                int* __restrict__ ngt,
                                                float* __restrict__ vk_arr) {
    const int b = blockIdx.x, t = threadIdx.x;
    __shared__ int h[256];
    __shared__ int ss[256];
    __shared__ int sres[2];
    __shared__ unsigned int win[GG];
    __shared__ int s_np_extra, s_np;
    __shared__ float s_pb_extra, s_loc_extra;
    __shared__ float sfs[4];
    __shared__ int sfc[4];
    h[t] = hist0[b * 256 + t];
    if (t == 0) { s_np_extra = 0; s_pb_extra = 0.0f; s_loc_extra = 0.0f; }
    if (t < GG) win[t] = 0xFFFFFFFFu - (unsigned int)(packed[b * GG + t] & 0xFFFFFFFFull);
    __syncthreads();
    // force-positive patch (<=32 winner anchors; dedup; bit-identical argmax recompute)
    if (t < GG) {
        unsigned int a = win[t];
        bool dup = false;
        for (int gp = 0; gp < t; ++gp) dup |= (win[gp] == a);
        if (!dup) {
            float4 an = anchors[a];
            float aa = __fmul_rn(__fsub_rn(an.z, an.x), __fsub_rn(an.w, an.y));
            float bi = -1.0f; int bix = 0;
            for (int gg = 0; gg < GG; ++gg) {
                float4 gv = gt[b * GG + gg];
                float ag = __fmul_rn(__fsub_rn(gv.z, gv.x), __fsub_rn(gv.w, gv.y));
                float iou = iou_exact(an.x, an.y, an.z, an.w, aa, gv.x, gv.y, gv.z, gv.w, ag);
                if (iou > bi) { bi = iou; bix = gg; }
            }
            if (!(bi > 0.5f)) {   // newly forced positive
                const int idx = b * AA + (int)a;
                float p = conf[idx];
                float nb = -fmaxf(log1pf(-p), -100.0f);
                atomicSub(&h[(int)(__float_as_uint(nb) >> 24)], 1);
                neg_bce[idx] = 0.0f;
                atomicAdd(&s_pb_extra, -fmaxf(logf(p), -100.0f));
                atomicAdd(&s_loc_extra, loc_term(bbox[idx], gt[b * GG + bix]));
                atomicAdd(&s_np_extra, 1);
            }
        }
    }
    __threadfence_block();
    __syncthreads();
    if (t == 0) {
        int np = num_pos[b] + s_np_extra;     // only this block touches image b now
        num_pos[b] = np;
        s_np = np;
        if (s_pb_extra != 0.0f) posbce[b] += s_pb_extra;
        if (s_loc_extra != 0.0f) loc_sum[b] += s_loc_extra;
    }
    __syncthreads();
    const int np = s_np;
    int k = min(3 * np, AA - np);
    if (k <= 0) return;                       // negsum/ngt stay 0 (memset); k_final gates vk on k0>0
    unsigned int prefix = 0;
    scan_level(h, t, ss, sres, &prefix, &k, 24);
    const float* __restrict__ nbp = neg_bce + (size_t)b * AA;
    for (int lvl = 1; lvl <= 3; ++lvl) {
        const int shift = 24 - 8 * lvl;
        const unsigned int pmask = 0xFFFFFFFFu << (shift + 8);
        h[t] = 0;
        __syncthreads();
        for (int i = 0; i < AA / 256; ++i) {
            unsigned int bits = __float_as_uint(nbp[i * 256 + t]);
            if ((bits & pmask) == prefix) atomicAdd(&h[(bits >> shift) & 0xFFu], 1);
        }
        __syncthreads();
        scan_level(h, t, ss, sres, &prefix, &k, shift);
    }
    const float vk = __uint_as_float(prefix);
    float s = 0.0f; int c = 0;
    for (int i = 0; i < AA / 256; ++i) {
        float v = nbp[i * 256 + t];
        if (v > vk) { s += v; c++; }
    }
#pragma unroll
    for (int off = 32; off; off >>= 1) { s += __shfl_xor(s, off, 64); c += __shfl_xor(c, off, 64); }
    const int lane = t & 63, wv = t >> 6;
    if (lane == 0) { sfs[wv] = s; sfc[wv] = c; }
    __syncthreads();
    if (t == 0) {
        negsum[b] = sfs[0] + sfs[1] + sfs[2] + sfs[3];
        ngt[b]    = sfc[0] + sfc[1] + sfc[2] + sfc[3];
        vk_arr[b] = vk;
    }
}

// ---------------- K3: trivial final combine ----------------
__global__ void k_final(const int* __restrict__ num_pos,
                        const float* __restrict__ loc_sum,
                        const float* __restrict__ posbce,
                        const float* __restrict__ negsum,
                        const int* __restrict__ ngt,
                        const float* __restrict__ vk_arr,
                        const int* __restrict__ pred_cnt,
                        const float* __restrict__ miou_s,
                        const int* __restrict__ miou_c,
                        float* __restrict__ out) {
    if (threadIdx.x == 0) {
        int npos_t = 0; float loc_t = 0.0f, conf_t = 0.0f, cnt_t = 0.0f;
        for (int b = 0; b < BB; ++b) {
            int np_ = num_pos[b];
            int k0 = min(3 * np_, AA - np_);
            float add = posbce[b] + negsum[b];
            if (k0 > 0) add += (float)(k0 - ngt[b]) * vk_arr[b];
            conf_t += add;
            npos_t += np_;
            loc_t += loc_sum[b];
            float diff = fabsf((float)(pred_cnt[b] - GG));
            cnt_t += (diff <= 3.0f) ? diff * 0.2f
                                    : 0.6f + 0.2f * logf(fmaxf(diff - 2.0f, 1.0f));
        }
        float total_count = cnt_t / (float)BB;
        float npos = (float)max(1, npos_t);
        float total_loc = loc_t / npos;
        float total_conf = conf_t / npos;
        int C = *miou_c;
        float mean_iou = (C > 0) ? (*miou_s / (float)max(C, 1)) : 0.1f;
        float q = fminf(fmaxf(1.0f - mean_iou, 0.1f), 0.9f);
        float dyn = 1.0f + q;
        out[0] = dyn * total_loc + total_conf + 0.2f * total_count;
        out[1] = total_conf;
        out[2] = total_loc;
        out[3] = total_count;
        out[4] = mean_iou;
    }
}

extern "C" void kernel_launch(void* const* d_in, const int* in_sizes, int n_in,
                              void* d_out, int out_size, void* d_ws, size_t ws_size,
                              hipStream_t stream) {
    (void)in_sizes; (void)n_in; (void)out_size; (void)ws_size;
    const float* bbox    = (const float*)d_in[0];
    const float* conf    = (const float*)d_in[1];
    const float* anchors = (const float*)d_in[2];
    const float* gt      = (const float*)d_in[3];
    char* ws = (char*)d_ws;
    unsigned long long* packed = (unsigned long long*)(ws + OFF_PACKED);
    int*   hist     = (int*)(ws + OFF_HIST);
    int*   num_pos  = (int*)(ws + OFF_NUMPOS);
    float* loc_sum  = (float*)(ws + OFF_LOCSUM);
    float* posbce   = (float*)(ws + OFF_POSBCE);
    int*   pred_cnt = (int*)(ws + OFF_PREDCNT);
    float* negsum   = (float*)(ws + OFF_NEGSUM);
    int*   ngt      = (int*)(ws + OFF_NGT);
    float* miou_s   = (float*)(ws + OFF_MIOU_S);
    int*   miou_c   = (int*)(ws + OFF_MIOU_C);
    float* vk_arr   = (float*)(ws + OFF_VK);
    float* neg_bce  = (float*)(ws + OFF_NEGBCE);

    hipMemsetAsync(d_ws, 0, MEMSET_BYTES, stream);
    k_main<<<dim3(64, BB), 256, 0, stream>>>((const float4*)bbox, conf,
                                             (const float4*)anchors, (const float4*)gt,
                                             packed, neg_bce,
                                             hist, num_pos, loc_sum, posbce, pred_cnt,
                                             miou_s, miou_c);
    k_select<<<BB, 256, 0, stream>>>((const float4*)bbox, conf,
                                     (const float4*)anchors, (const float4*)gt,
                                     packed, hist, neg_bce,
                                     num_pos, loc_sum, posbce, negsum, ngt, vk_arr);
    k_final<<<1, 64, 0, stream>>>(num_pos, loc_sum, posbce, negsum, ngt, vk_arr,
                                  pred_cnt, miou_s, miou_c, (float*)d_out);
}